// Round 1
// baseline (626.238 us; speedup 1.0000x reference)
//
#include <hip/hip_runtime.h>

#define NNODES 50000
#define RREL 51
#define FIN 32
#define EDIM 32
#define CDIM 16
#define BB 30
#define NNZ_ 2000000

// ---------------- weight build: w[r] = sum_b comps[r,b] * bases[b] ----------------
__global__ void k_weights(const float* __restrict__ comps1, const float* __restrict__ bases1,
                          const float* __restrict__ comps2, const float* __restrict__ bases2,
                          float* __restrict__ w1, float* __restrict__ w2) {
    int i = blockIdx.x * 256 + threadIdx.x;
    if (i < RREL * FIN * EDIM) {          // (R, F, E)
        int r = i >> 10, fe = i & 1023;
        float acc = 0.f;
#pragma unroll
        for (int b = 0; b < BB; b++) acc += comps1[r * BB + b] * bases1[b * 1024 + fe];
        w1[i] = acc;
    }
    if (i < RREL * EDIM * CDIM) {         // (R, E, C)
        int r = i >> 9, ec = i & 511;
        float acc = 0.f;
#pragma unroll
        for (int b = 0; b < BB; b++) acc += comps2[r * BB + b] * bases2[b * 512 + ec];
        w2[i] = acc;
    }
}

// ---------------- counting sort of edges by relation ----------------
__global__ void k_hist(const int* __restrict__ rows, int* __restrict__ rel_cnt) {
    __shared__ int lc[RREL];
    if (threadIdx.x < RREL) lc[threadIdx.x] = 0;
    __syncthreads();
    int stride = gridDim.x * blockDim.x;
    for (int k = blockIdx.x * blockDim.x + threadIdx.x; k < NNZ_; k += stride) {
        int rel = rows[k] / NNODES;
        atomicAdd(&lc[rel], 1);
    }
    __syncthreads();
    if (threadIdx.x < RREL) atomicAdd(&rel_cnt[threadIdx.x], lc[threadIdx.x]);
}

__global__ void k_prefix(const int* __restrict__ rel_cnt, int* __restrict__ rel_base) {
    if (threadIdx.x == 0) {
        int acc = 0;
        for (int r = 0; r < RREL; r++) { rel_base[r] = acc; acc += rel_cnt[r]; }
    }
}

__global__ void k_scatter(const int* __restrict__ rows, const int* __restrict__ cols,
                          const float* __restrict__ vals, int* __restrict__ rel_base,
                          int* __restrict__ s_key, int* __restrict__ s_src,
                          float* __restrict__ s_val) {
    __shared__ int lcnt[RREL], lbase[RREL];
    int t = threadIdx.x;
    int base = blockIdx.x * 2048;
    if (t < RREL) lcnt[t] = 0;
    __syncthreads();
    int relv[8];
#pragma unroll
    for (int i = 0; i < 8; i++) {
        int k = base + i * 256 + t;
        if (k < NNZ_) { int r = rows[k] / NNODES; relv[i] = r; atomicAdd(&lcnt[r], 1); }
        else relv[i] = -1;
    }
    __syncthreads();
    if (t < RREL) lbase[t] = atomicAdd(&rel_base[t], lcnt[t]);
    __syncthreads();
    if (t < RREL) lcnt[t] = 0;
    __syncthreads();
#pragma unroll
    for (int i = 0; i < 8; i++) {
        int k = base + i * 256 + t;
        if (k < NNZ_) {
            int r = relv[i];
            int pos = lbase[r] + atomicAdd(&lcnt[r], 1);
            s_key[pos] = (r << 16) | (rows[k] - r * NNODES);   // dst < 50000 fits 16 bits
            s_src[pos] = cols[k];
            s_val[pos] = vals[k];
        }
    }
}

// ---------------- fused edge kernel: y = val * (X[src] @ W[rel]) scattered to out[dst] ----
template <int FO>
__device__ __forceinline__ void matvec_acc(const float* __restrict__ wb,
                                           const float (&xr)[32], float (&acc)[FO]) {
#pragma unroll
    for (int f = 0; f < 32; f++) {
        float xf = xr[f];
#pragma unroll
        for (int e = 0; e < FO; e++) acc[e] = fmaf(xf, wb[f * FO + e], acc[e]);
    }
}

template <int FO>
__global__ __launch_bounds__(256) void k_edge(const int* __restrict__ s_key,
                                              const int* __restrict__ s_src,
                                              const float* __restrict__ s_val,
                                              const float* __restrict__ X,
                                              const float* __restrict__ W,
                                              float* __restrict__ out) {
    __shared__ float Y[4][64 * (FO + 1)];
    __shared__ int D[4][64];
    int t = threadIdx.x;
    int lane = t & 63, wv = t >> 6;
    int k = blockIdx.x * 256 + t;
    int key = 0, src = 0;
    float v = 0.f;
    if (k < NNZ_) { key = s_key[k]; src = s_src[k]; v = s_val[k]; }
    int rel = key >> 16, dst = key & 0xffff;

    float xr[32];
    const float4* xp = (const float4*)X + src * 8;
#pragma unroll
    for (int i = 0; i < 8; i++) {
        float4 q = xp[i];
        xr[4 * i] = q.x; xr[4 * i + 1] = q.y; xr[4 * i + 2] = q.z; xr[4 * i + 3] = q.w;
    }
    float acc[FO];
#pragma unroll
    for (int e = 0; e < FO; e++) acc[e] = 0.f;

    int rel_u = __builtin_amdgcn_readfirstlane(rel);
    if (__all(rel == rel_u)) {
        matvec_acc<FO>(W + rel_u * (32 * FO), xr, acc);   // uniform -> scalar loads
    } else {
        matvec_acc<FO>(W + rel * (32 * FO), xr, acc);     // boundary waves (rare)
    }

    // LDS transpose so atomics are line-coalesced
    float* y = &Y[wv][0];
#pragma unroll
    for (int e = 0; e < FO; e++) y[lane * (FO + 1) + e] = v * acc[e];
    D[wv][lane] = dst;
    __syncthreads();

    const int GP = 64 / FO;       // edges per atomic instruction
    int e = lane & (FO - 1);
    int g = lane / FO;
#pragma unroll
    for (int j = 0; j < FO; j++) {
        int edge = j * GP + g;
        float val = y[edge * (FO + 1) + e];
        int d = D[wv][edge];
        atomicAdd(&out[d * FO + e], val);
    }
}

// ---------------- elementwise epilogues ----------------
__global__ void k_relu(float* __restrict__ h1, const float* __restrict__ bias1) {
    int i = blockIdx.x * 256 + threadIdx.x;
    if (i >= NNODES * EDIM / 4) return;
    float4 v = ((float4*)h1)[i];
    float4 b = ((const float4*)bias1)[i & 7];
    v.x = fmaxf(v.x + b.x, 0.f);
    v.y = fmaxf(v.y + b.y, 0.f);
    v.z = fmaxf(v.z + b.z, 0.f);
    v.w = fmaxf(v.w + b.w, 0.f);
    ((float4*)h1)[i] = v;
}

__global__ void k_out(const float* __restrict__ h2, const float* __restrict__ bias2,
                      float* __restrict__ out) {
    int i = blockIdx.x * 256 + threadIdx.x;
    if (i >= NNODES * CDIM / 4) return;
    float4 v = ((const float4*)h2)[i];
    float4 b = ((const float4*)bias2)[i & 3];
    v.x += b.x; v.y += b.y; v.z += b.z; v.w += b.w;
    ((float4*)out)[i] = v;
}

extern "C" void kernel_launch(void* const* d_in, const int* in_sizes, int n_in,
                              void* d_out, int out_size, void* d_ws, size_t ws_size,
                              hipStream_t stream) {
    const float* features = (const float*)d_in[0];
    const float* vals     = (const float*)d_in[1];
    const float* comps1   = (const float*)d_in[2];
    const float* bases1   = (const float*)d_in[3];
    const float* bias1    = (const float*)d_in[4];
    const float* comps2   = (const float*)d_in[5];
    const float* bases2   = (const float*)d_in[6];
    const float* bias2    = (const float*)d_in[7];
    const int*   rows     = (const int*)d_in[8];
    const int*   cols     = (const int*)d_in[9];
    float* out = (float*)d_out;

    // workspace layout (~34 MB)
    float* ws    = (float*)d_ws;
    float* w1    = ws;                          // 52224
    float* w2    = w1 + 52224;                  // 26112
    float* h1    = w2 + 26112;                  // 1,600,000
    float* h2    = h1 + 1600000;                // 800,000
    int*   s_key = (int*)(h2 + 800000);         // NNZ
    int*   s_src = s_key + NNZ_;                // NNZ
    float* s_val = (float*)(s_src + NNZ_);      // NNZ
    int*   rel_cnt  = (int*)(s_val + NNZ_);     // 51
    int*   rel_base = rel_cnt + RREL;           // 51

    hipMemsetAsync(h1, 0, (size_t)(1600000 + 800000) * sizeof(float), stream);
    hipMemsetAsync(rel_cnt, 0, 2 * RREL * sizeof(int), stream);

    k_weights<<<(RREL * FIN * EDIM + 255) / 256, 256, 0, stream>>>(comps1, bases1, comps2, bases2, w1, w2);
    k_hist<<<512, 256, 0, stream>>>(rows, rel_cnt);
    k_prefix<<<1, 64, 0, stream>>>(rel_cnt, rel_base);
    k_scatter<<<(NNZ_ + 2047) / 2048, 256, 0, stream>>>(rows, cols, vals, rel_base, s_key, s_src, s_val);

    k_edge<EDIM><<<(NNZ_ + 255) / 256, 256, 0, stream>>>(s_key, s_src, s_val, features, w1, h1);
    k_relu<<<(NNODES * EDIM / 4 + 255) / 256, 256, 0, stream>>>(h1, bias1);
    k_edge<CDIM><<<(NNZ_ + 255) / 256, 256, 0, stream>>>(s_key, s_src, s_val, h1, w2, h2);
    k_out<<<(NNODES * CDIM / 4 + 255) / 256, 256, 0, stream>>>(h2, bias2, out);
}